// Round 2
// baseline (908.838 us; speedup 1.0000x reference)
//
#include <hip/hip_runtime.h>

// NodeMPNNLayer — bf16-MFMA + dst-sorted edges, high-occupancy edge kernel.
//   prep_weights: W1b/W2/W3 -> bf16, transposed [n][k], XOR-swizzled, in ws.
//   pq_kernel:    P' = x@W1[0:128] + b1,  Q = x@W1[256:384]   (bf16 in ws)
//   hist/scan/scatter: counting-sort edge ids by dst -> perm[], exact cnt[].
//   edge_mfma:    128 sorted edges/block, 34.5 KB LDS -> 4 blocks/CU.
//                 B-frags straight from global WT (L1/L2 broadcast).
//                 Q[src] staged coalesced into LDS; in-place epilogues.
//                 Scatter via 2-chunk in-LDS segmented reduction.
//   node_fused:   dh=sums/max(cnt,1); LN; FF; LN  (fp32, 8 nodes/block).

#define NE 640000
#define NN 10000
#define DD 128
#define HIDN 256
#define EPSF 1e-6f

typedef __attribute__((ext_vector_type(8))) short short8;
typedef __attribute__((ext_vector_type(4))) float f32x4;

__device__ __forceinline__ unsigned short f2bf(float f) {
    union { float f; unsigned int u; } v; v.f = f;
    unsigned int r = v.u + 0x7FFFu + ((v.u >> 16) & 1u);
    return (unsigned short)(r >> 16);
}
__device__ __forceinline__ float bf2f(unsigned short h) {
    union { unsigned int u; float f; } v; v.u = ((unsigned int)h) << 16;
    return v.f;
}

// ---------------------------------------------------------------------------
// Weight prep: WT[layer][n][swz(k)] = bf16(W[k][n]); swizzle g' = (k>>3)^(n&7)
// ---------------------------------------------------------------------------
__global__ void prep_weights(const float* __restrict__ W1,
                             const float* __restrict__ W2,
                             const float* __restrict__ W3,
                             unsigned short* __restrict__ WT)
{
    int g = blockIdx.x * 256 + threadIdx.x;      // 3*16384 = 49152
    int layer = g >> 14, r = g & 16383;
    int n = r >> 7, k = r & 127;
    const float* W = (layer == 0) ? (W1 + 128 * DD) : (layer == 1 ? W2 : W3);
    WT[layer * 16384 + n * 128 + ((((k >> 3) ^ (n & 7)) << 3) | (k & 7))] =
        f2bf(W[k * DD + n]);
}

// ---------------------------------------------------------------------------
// P' = x @ W1[0:128] + b1 ; Q = x @ W1[256:384]   (outputs bf16)
// ---------------------------------------------------------------------------
__global__ __launch_bounds__(256, 2)
void pq_kernel(const float* __restrict__ x, const float* __restrict__ W1,
               const float* __restrict__ b1,
               unsigned short* __restrict__ Pb, unsigned short* __restrict__ Qb)
{
    __shared__ float sXT[128 * 68];   // x^T tile, [k][row], stride 68
    __shared__ float sB[32 * 128];
    const int t = threadIdx.x;
    const int nb = blockIdx.x * 64;
    const int r0 = (t >> 4) << 2, c0 = (t & 15) << 3;

#pragma unroll
    for (int p = 0; p < 8; ++p) {
        int f = t + p * 256;                   // 2048 float4 = 64 rows x 32
        int row = f >> 5, c4 = (f & 31) << 2;
        int node = nb + row; if (node >= NN) node = NN - 1;
        float4 v = *(const float4*)(x + (long)node * DD + c4);
        sXT[(c4 + 0) * 68 + row] = v.x;
        sXT[(c4 + 1) * 68 + row] = v.y;
        sXT[(c4 + 2) * 68 + row] = v.z;
        sXT[(c4 + 3) * 68 + row] = v.w;
    }

    for (int pass = 0; pass < 2; ++pass) {
        const float* W = W1 + (pass == 0 ? 0 : 256 * DD);
        float acc[4][8];
#pragma unroll
        for (int i = 0; i < 4; ++i)
#pragma unroll
            for (int j = 0; j < 8; ++j) acc[i][j] = 0.f;

        for (int kc = 0; kc < 4; ++kc) {
            __syncthreads();
#pragma unroll
            for (int p = 0; p < 4; ++p) {
                int f = t + p * 256;           // 1024 float4 = 32 k x 32
                int kr = f >> 5, col = (f & 31) << 2;
                *(float4*)(sB + kr * 128 + col) =
                    *(const float4*)(W + (long)(kc * 32 + kr) * DD + col);
            }
            __syncthreads();
#pragma unroll 4
            for (int k = 0; k < 32; ++k) {
                float4 a  = *(const float4*)(sXT + (kc * 32 + k) * 68 + r0);
                float4 bl = *(const float4*)(sB + k * 128 + c0);
                float4 bh = *(const float4*)(sB + k * 128 + c0 + 4);
                float av[4] = {a.x, a.y, a.z, a.w};
                float bv[8] = {bl.x, bl.y, bl.z, bl.w, bh.x, bh.y, bh.z, bh.w};
#pragma unroll
                for (int i = 0; i < 4; ++i)
#pragma unroll
                    for (int j = 0; j < 8; ++j)
                        acc[i][j] = fmaf(av[i], bv[j], acc[i][j]);
            }
        }
        unsigned short* Out = (pass == 0) ? Pb : Qb;
#pragma unroll
        for (int i = 0; i < 4; ++i) {
            int node = nb + r0 + i;
            if (node < NN) {
                unsigned short tmp[8];
#pragma unroll
                for (int j = 0; j < 8; ++j) {
                    float v = acc[i][j] + (pass == 0 ? b1[c0 + j] : 0.f);
                    tmp[j] = f2bf(v);
                }
                *(uint4*)(Out + (long)node * 128 + c0) = *(uint4*)tmp;
            }
        }
    }
}

// ---------------------------------------------------------------------------
// CSR build: counting sort of edge ids by dst.
// ---------------------------------------------------------------------------
__global__ void hist_kernel(const int* __restrict__ ei, int* __restrict__ cursor)
{
    int e = blockIdx.x * 256 + threadIdx.x;
    if (e < NE) atomicAdd(cursor + ei[(long)NE + e], 1);
}

// single block: exclusive scan of counts -> cursor (=offsets), cnt = (float)count
__global__ __launch_bounds__(256)
void scan_kernel(int* __restrict__ cursor, float* __restrict__ cnt)
{
    __shared__ int sp[256];
    const int t = threadIdx.x;
    const int base = t * 40;                  // 256*40 = 10240 >= NN
    int v[40], loc[40];
    int s = 0;
#pragma unroll
    for (int i = 0; i < 40; ++i) {
        int n = base + i;
        v[i] = (n < NN) ? cursor[n] : 0;
        loc[i] = s; s += v[i];
    }
    sp[t] = s;
    __syncthreads();
    // inclusive Hillis-Steele scan over 256 partials
    for (int off = 1; off < 256; off <<= 1) {
        int x = 0;
        if (t >= off) x = sp[t - off];
        __syncthreads();
        sp[t] += x;
        __syncthreads();
    }
    int excl = sp[t] - s;
#pragma unroll
    for (int i = 0; i < 40; ++i) {
        int n = base + i;
        if (n < NN) {
            cursor[n] = excl + loc[i];        // exclusive offset
            cnt[n] = (float)v[i];             // exact in-degree
        }
    }
}

__global__ void scatter_kernel(const int* __restrict__ ei,
                               int* __restrict__ cursor, int* __restrict__ perm)
{
    int e = blockIdx.x * 256 + threadIdx.x;
    if (e < NE) {
        int d = ei[(long)NE + e];
        int p = atomicAdd(cursor + d, 1);
        perm[p] = e;
    }
}

// ---------------------------------------------------------------------------
// Edge kernel: 128 sorted edges/block, 4 waves; wave w owns rows 32w..32w+31.
// LDS: 1.5 KB aux + 33 KB tile (bf16 A / fp32 sM overlay) = 34.5 KB
//   -> 4 blocks/CU. B-fragments read directly from global WT.
// ---------------------------------------------------------------------------
__device__ __forceinline__ const short8* frag(const unsigned short* buf,
                                              int row, int kc, int q)
{
    int g = (kc * 4 + q) ^ (row & 7);
    return (const short8*)(buf + row * 128 + g * 8);
}

__global__ __launch_bounds__(256, 4)
void edge_mfma(const float* __restrict__ ea, const int* __restrict__ ei,
               const int* __restrict__ perm,
               const unsigned short* __restrict__ WT,
               const unsigned short* __restrict__ Pb,
               const unsigned short* __restrict__ Qb,
               const float* __restrict__ b2, const float* __restrict__ b3,
               float* __restrict__ sums)
{
    __shared__ __align__(16) char smem[1536 + 64 * 132 * 4];   // 35328 B
    int*            sE   = (int*)smem;                  // [128] edge ids
    int*            sDst = (int*)(smem + 512);          // [128] dst node
    int*            sSrc = (int*)(smem + 1024);         // [128] src node
    unsigned short* sA = (unsigned short*)(smem + 1536);// 32 KB bf16 (swz)
    float*          sM = (float*)(smem + 1536);         // 64x132 fp32 overlay

    const int t = threadIdx.x;
    const int wave = t >> 6, lane = t & 63;
    const int ln = lane & 15, q = lane >> 4;
    const int r0 = wave * 32;
    const long pbase = (long)blockIdx.x * 128;

    if (t < 128) {
        int e = perm[pbase + t];
        sE[t] = e;
        sDst[t] = ei[(long)NE + e];
        sSrc[t] = ei[e];
    }
    __syncthreads();

    // stage A = bf16(ea rows, gathered via perm), swizzled; 512B/row contiguous
#pragma unroll
    for (int p = 0; p < 16; ++p) {
        int f = t + p * 256;                   // 4096 float4 = 128 x 32
        int row = f >> 5, c4 = (f & 31) << 2;
        float4 v = *(const float4*)(ea + (long)sE[row] * DD + c4);
        uint2 pk;
        pk.x = (unsigned)f2bf(v.x) | ((unsigned)f2bf(v.y) << 16);
        pk.y = (unsigned)f2bf(v.z) | ((unsigned)f2bf(v.w) << 16);
        int addr = row * 128 + ((((c4 >> 3) ^ (row & 7)) << 3) | (c4 & 7));
        *(uint2*)(sA + addr) = pk;
    }
    __syncthreads();

    f32x4 acc[2][8];

    // ---- layer 1: bf16(ea) @ W1b^T ; B-frags from global WT ----
#pragma unroll
    for (int rt = 0; rt < 2; ++rt)
#pragma unroll
        for (int ct = 0; ct < 8; ++ct) acc[rt][ct] = (f32x4)(0.f);
#pragma unroll
    for (int kc = 0; kc < 4; ++kc) {
        short8 a0 = *frag(sA, r0 + ln,      kc, q);
        short8 a1 = *frag(sA, r0 + 16 + ln, kc, q);
#pragma unroll
        for (int ct = 0; ct < 8; ++ct) {
            short8 b = *frag(WT, ct * 16 + ln, kc, q);
            acc[0][ct] = __builtin_amdgcn_mfma_f32_16x16x32_bf16(a0, b, acc[0][ct], 0, 0, 0);
            acc[1][ct] = __builtin_amdgcn_mfma_f32_16x16x32_bf16(a1, b, acc[1][ct], 0, 0, 0);
        }
    }
    __syncthreads();   // all waves done reading sA before Q overwrite

    // stage Q[src] rows into sA (swizzled), coalesced 16B/lane
#pragma unroll
    for (int p = 0; p < 8; ++p) {
        int f = t + p * 256;                   // 2048 uint4 = 128 rows x 16
        int row = f >> 4, g = f & 15;
        uint4 v = *(const uint4*)(Qb + (long)sSrc[row] * DD + g * 8);
        *(uint4*)(sA + row * 128 + ((g ^ (row & 7)) << 3)) = v;
    }
    __syncthreads();

    // epilogue-1: relu(acc + P'[dst] + Q[src]) -> sA in place (lane-private)
#pragma unroll
    for (int rt = 0; rt < 2; ++rt)
#pragma unroll
        for (int rg = 0; rg < 4; ++rg) {
            int row = r0 + rt * 16 + q * 4 + rg;
            long dof = (long)sDst[row] * DD;
#pragma unroll
            for (int ct = 0; ct < 8; ++ct) {
                int col = ct * 16 + ln;
                int slot = row * 128 + ((((col >> 3) ^ (row & 7)) << 3) | (col & 7));
                float v = acc[rt][ct][rg] + bf2f(Pb[dof + col]) + bf2f(sA[slot]);
                sA[slot] = f2bf(fmaxf(v, 0.f));
            }
        }
    // wave-private rows: no barrier needed before layer 2

    // ---- layer 2 ----
#pragma unroll
    for (int rt = 0; rt < 2; ++rt)
#pragma unroll
        for (int ct = 0; ct < 8; ++ct) acc[rt][ct] = (f32x4)(0.f);
#pragma unroll
    for (int kc = 0; kc < 4; ++kc) {
        short8 a0 = *frag(sA, r0 + ln,      kc, q);
        short8 a1 = *frag(sA, r0 + 16 + ln, kc, q);
#pragma unroll
        for (int ct = 0; ct < 8; ++ct) {
            short8 b = *frag(WT + 16384, ct * 16 + ln, kc, q);
            acc[0][ct] = __builtin_amdgcn_mfma_f32_16x16x32_bf16(a0, b, acc[0][ct], 0, 0, 0);
            acc[1][ct] = __builtin_amdgcn_mfma_f32_16x16x32_bf16(a1, b, acc[1][ct], 0, 0, 0);
        }
    }
    // epilogue-2: relu(acc + b2) -> sA in place (lane-private)
    float bv2[8];
#pragma unroll
    for (int ct = 0; ct < 8; ++ct) bv2[ct] = b2[ct * 16 + ln];
#pragma unroll
    for (int rt = 0; rt < 2; ++rt)
#pragma unroll
        for (int rg = 0; rg < 4; ++rg) {
            int row = r0 + rt * 16 + q * 4 + rg;
#pragma unroll
            for (int ct = 0; ct < 8; ++ct) {
                int col = ct * 16 + ln;
                int slot = row * 128 + ((((col >> 3) ^ (row & 7)) << 3) | (col & 7));
                sA[slot] = f2bf(fmaxf(acc[rt][ct][rg] + bv2[ct], 0.f));
            }
        }

    // ---- layer 3 ----
#pragma unroll
    for (int rt = 0; rt < 2; ++rt)
#pragma unroll
        for (int ct = 0; ct < 8; ++ct) acc[rt][ct] = (f32x4)(0.f);
#pragma unroll
    for (int kc = 0; kc < 4; ++kc) {
        short8 a0 = *frag(sA, r0 + ln,      kc, q);
        short8 a1 = *frag(sA, r0 + 16 + ln, kc, q);
#pragma unroll
        for (int ct = 0; ct < 8; ++ct) {
            short8 b = *frag(WT + 2 * 16384, ct * 16 + ln, kc, q);
            acc[0][ct] = __builtin_amdgcn_mfma_f32_16x16x32_bf16(a0, b, acc[0][ct], 0, 0, 0);
            acc[1][ct] = __builtin_amdgcn_mfma_f32_16x16x32_bf16(a1, b, acc[1][ct], 0, 0, 0);
        }
    }
    __syncthreads();   // sA dead; sM overlay begins

    // epilogue-3: two 64-row chunks; fp32 stage into sM (stride 132), then
    // segmented reduction over sorted dst -> few atomics.
    float bv3[8];
#pragma unroll
    for (int ct = 0; ct < 8; ++ct) bv3[ct] = b3[ct * 16 + ln];

    // chunk 0: rows 0..63 (waves 0,1)
    if (wave < 2) {
#pragma unroll
        for (int rt = 0; rt < 2; ++rt)
#pragma unroll
            for (int rg = 0; rg < 4; ++rg) {
                int row = r0 + rt * 16 + q * 4 + rg;
#pragma unroll
                for (int ct = 0; ct < 8; ++ct)
                    sM[row * 132 + ct * 16 + ln] = acc[rt][ct][rg] + bv3[ct];
            }
    }
    __syncthreads();
    {
        const int c = t & 127, h = t >> 7;
        const int rb = h * 32;
        float a = 0.f;
        int cur = sDst[rb];
#pragma unroll 8
        for (int r = rb; r < rb + 32; ++r) {
            int d = sDst[r];                   // LDS broadcast
            if (d != cur) {
                atomicAdd(sums + (long)cur * DD + c, a);
                a = 0.f; cur = d;
            }
            a += sM[r * 132 + c];
        }
        atomicAdd(sums + (long)cur * DD + c, a);
    }
    __syncthreads();
    // chunk 1: rows 64..127 (waves 2,3)
    if (wave >= 2) {
#pragma unroll
        for (int rt = 0; rt < 2; ++rt)
#pragma unroll
            for (int rg = 0; rg < 4; ++rg) {
                int row = r0 + rt * 16 + q * 4 + rg;   // 64..127
#pragma unroll
                for (int ct = 0; ct < 8; ++ct)
                    sM[(row - 64) * 132 + ct * 16 + ln] = acc[rt][ct][rg] + bv3[ct];
            }
    }
    __syncthreads();
    {
        const int c = t & 127, h = t >> 7;
        const int rb = h * 32;
        float a = 0.f;
        int cur = sDst[64 + rb];
#pragma unroll 8
        for (int r = rb; r < rb + 32; ++r) {
            int d = sDst[64 + r];
            if (d != cur) {
                atomicAdd(sums + (long)cur * DD + c, a);
                a = 0.f; cur = d;
            }
            a += sM[r * 132 + c];
        }
        atomicAdd(sums + (long)cur * DD + c, a);
    }
}

// ---------------------------------------------------------------------------
// Node stage: dh + LN1 + FF + LN2, fp32, 8 nodes/block.
// ---------------------------------------------------------------------------
__global__ __launch_bounds__(256)
void node_fused(const float* __restrict__ x,
                const float* __restrict__ sums, const float* __restrict__ cnt,
                const float* __restrict__ F1, const float* __restrict__ bf1,
                const float* __restrict__ F2, const float* __restrict__ bf2,
                const float* __restrict__ g0, const float* __restrict__ be0,
                const float* __restrict__ g1, const float* __restrict__ be1,
                float* __restrict__ out)
{
    constexpr int NPB = 8;
    __shared__ float sh[NPB][DD];
    __shared__ float shid[NPB][HIDN];
    __shared__ float sz[NPB][DD];

    const int t = threadIdx.x;
    const int wave = t >> 6, lane = t & 63;
    const int half = lane >> 5, l2 = lane & 31;
    const int nl = wave * 2 + half;
    const int node = blockIdx.x * NPB + nl;
    const long base = (long)node * DD;

    float inv = 1.0f / fmaxf(cnt[node], 1.0f);
    float y[4], s = 0.f, ss = 0.f;
#pragma unroll
    for (int e = 0; e < 4; ++e) {
        int c = l2 + 32 * e;
        y[e] = x[base + c] + sums[base + c] * inv;
        s += y[e]; ss += y[e] * y[e];
    }
#pragma unroll
    for (int off = 16; off > 0; off >>= 1) {
        s += __shfl_down(s, off, 32); ss += __shfl_down(ss, off, 32);
    }
    s = __shfl(s, 0, 32); ss = __shfl(ss, 0, 32);
    float mean = s * (1.0f / DD);
    float var  = ss * (1.0f / DD) - mean * mean;
    float rstd = rsqrtf(var + EPSF);
#pragma unroll
    for (int e = 0; e < 4; ++e) {
        int c = l2 + 32 * e;
        sh[nl][c] = (y[e] - mean) * rstd * g0[c] + be0[c];
    }
    __syncthreads();

    float hacc[NPB];
    float bb = bf1[t];
#pragma unroll
    for (int v = 0; v < NPB; ++v) hacc[v] = bb;
    for (int k = 0; k < DD; ++k) {
        float wv = F1[(long)k * HIDN + t];
#pragma unroll
        for (int v = 0; v < NPB; ++v) hacc[v] = fmaf(sh[v][k], wv, hacc[v]);
    }
#pragma unroll
    for (int v = 0; v < NPB; ++v) shid[v][t] = fmaxf(hacc[v], 0.f);
    __syncthreads();

    const int col = t & (DD - 1);
    const int grp = (t >> 7) * 4;
    float o[4];
#pragma unroll
    for (int v = 0; v < 4; ++v) o[v] = bf2[col];
    for (int k = 0; k < HIDN; ++k) {
        float wv = F2[(long)k * DD + col];
#pragma unroll
        for (int v = 0; v < 4; ++v) o[v] = fmaf(shid[grp + v][k], wv, o[v]);
    }
#pragma unroll
    for (int v = 0; v < 4; ++v) sz[grp + v][col] = sh[grp + v][col] + o[v];
    __syncthreads();

    float z[4]; s = 0.f; ss = 0.f;
#pragma unroll
    for (int e = 0; e < 4; ++e) {
        int c = l2 + 32 * e;
        z[e] = sz[nl][c]; s += z[e]; ss += z[e] * z[e];
    }
#pragma unroll
    for (int off = 16; off > 0; off >>= 1) {
        s += __shfl_down(s, off, 32); ss += __shfl_down(ss, off, 32);
    }
    s = __shfl(s, 0, 32); ss = __shfl(ss, 0, 32);
    mean = s * (1.0f / DD);
    var  = ss * (1.0f / DD) - mean * mean;
    rstd = rsqrtf(var + EPSF);
#pragma unroll
    for (int e = 0; e < 4; ++e) {
        int c = l2 + 32 * e;
        out[base + c] = (z[e] - mean) * rstd * g1[c] + be1[c];
    }
}

extern "C" void kernel_launch(void* const* d_in, const int* in_sizes, int n_in,
                              void* d_out, int out_size, void* d_ws, size_t ws_size,
                              hipStream_t stream)
{
    const float* x   = (const float*)d_in[0];
    const int*   ei  = (const int*)  d_in[1];
    const float* ea  = (const float*)d_in[2];
    const float* W1  = (const float*)d_in[3];
    const float* b1  = (const float*)d_in[4];
    const float* W2  = (const float*)d_in[5];
    const float* b2  = (const float*)d_in[6];
    const float* W3  = (const float*)d_in[7];
    const float* b3  = (const float*)d_in[8];
    const float* F1  = (const float*)d_in[9];
    const float* bf1 = (const float*)d_in[10];
    const float* F2  = (const float*)d_in[11];
    const float* bf2 = (const float*)d_in[12];
    const float* g0  = (const float*)d_in[13];
    const float* be0 = (const float*)d_in[14];
    const float* g1  = (const float*)d_in[15];
    const float* be1 = (const float*)d_in[16];
    float* out = (float*)d_out;

    char* ws = (char*)d_ws;
    float*          sums   = (float*)(ws);                     // 5,120,000 B
    float*          cnt    = (float*)(ws + 5120000);           //    40,000 B
    unsigned short* WT     = (unsigned short*)(ws + 5160192);  //    98,304 B
    unsigned short* Pb     = (unsigned short*)(ws + 5258752);  // 2,560,000 B
    unsigned short* Qb     = (unsigned short*)(ws + 7818752);  // 2,560,000 B
    int*            cursor = (int*)(ws + 10378752);            //    40,000 B
    int*            perm   = (int*)(ws + 10418752);            // 2,560,000 B
    // total ~12.98 MB

    hipMemsetAsync(ws, 0, 5120000, stream);                    // sums
    hipMemsetAsync(ws + 10378752, 0, 40000, stream);           // cursor
    prep_weights<<<192, 256, 0, stream>>>(W1, W2, W3, WT);
    pq_kernel<<<(NN + 63) / 64, 256, 0, stream>>>(x, W1, b1, Pb, Qb);
    hist_kernel<<<NE / 256, 256, 0, stream>>>(ei, cursor);
    scan_kernel<<<1, 256, 0, stream>>>(cursor, cnt);
    scatter_kernel<<<NE / 256, 256, 0, stream>>>(ei, cursor, perm);
    edge_mfma<<<NE / 128, 256, 0, stream>>>(ea, ei, perm, WT, Pb, Qb,
                                            b2, b3, sums);
    node_fused<<<NN / 8, 256, 0, stream>>>(x, sums, cnt, F1, bf1, F2, bf2,
                                           g0, be0, g1, be1, out);
}

// Round 3
// 861.274 us; speedup vs baseline: 1.0552x; 1.0552x over previous
//
#include <hip/hip_runtime.h>

// NodeMPNNLayer — bf16-MFMA + dst-sorted edges, high-occupancy edge kernel.
//   prep_hist:    W1b/W2/W3 -> bf16 swizzled in ws  +  dst histogram.
//   pq_kernel:    P' = x@W1[0:128] + b1,  Q = x@W1[256:384]   (bf16 in ws)
//   scan/scatter: counting-sort edge ids by dst -> perm[], exact cnt[].
//   edge_mfma:    128 sorted edges/block, 34.5 KB LDS; B-frags from global
//                 WT (L2-hot); Q[src] staged coalesced; in-place epilogues;
//                 2-chunk in-LDS segmented reduction scatter.
//                 __launch_bounds__(256,2): (256,4) forced a 64-VGPR alloc
//                 -> massive scratch spills (+220 MB HBM, R2 regression).
//                 Natural alloc ~128 VGPR still allows 4 blocks/CU.
//   node_fused:   dh=sums/max(cnt,1); LN; FF; LN  (fp32, 8 nodes/block).

#define NE 640000
#define NN 10000
#define DD 128
#define HIDN 256
#define EPSF 1e-6f

typedef __attribute__((ext_vector_type(8))) short short8;
typedef __attribute__((ext_vector_type(4))) float f32x4;

__device__ __forceinline__ unsigned short f2bf(float f) {
    union { float f; unsigned int u; } v; v.f = f;
    unsigned int r = v.u + 0x7FFFu + ((v.u >> 16) & 1u);
    return (unsigned short)(r >> 16);
}
__device__ __forceinline__ float bf2f(unsigned short h) {
    union { unsigned int u; float f; } v; v.u = ((unsigned int)h) << 16;
    return v.f;
}

// ---------------------------------------------------------------------------
// Fused weight prep + dst histogram.  grid = NE/256 = 2500 blocks.
// Blocks 0..191 additionally convert one 256-chunk of weights.
// ---------------------------------------------------------------------------
__global__ void prep_hist(const float* __restrict__ W1,
                          const float* __restrict__ W2,
                          const float* __restrict__ W3,
                          unsigned short* __restrict__ WT,
                          const int* __restrict__ ei,
                          int* __restrict__ cursor)
{
    int e = blockIdx.x * 256 + threadIdx.x;
    if (e < NE) atomicAdd(cursor + ei[(long)NE + e], 1);
    if (blockIdx.x < 192) {
        int g = blockIdx.x * 256 + threadIdx.x;  // 3*16384 = 49152
        int layer = g >> 14, r = g & 16383;
        int n = r >> 7, k = r & 127;
        const float* W = (layer == 0) ? (W1 + 128 * DD) : (layer == 1 ? W2 : W3);
        WT[layer * 16384 + n * 128 + ((((k >> 3) ^ (n & 7)) << 3) | (k & 7))] =
            f2bf(W[k * DD + n]);
    }
}

// ---------------------------------------------------------------------------
// P' = x @ W1[0:128] + b1 ; Q = x @ W1[256:384]   (outputs bf16)
// ---------------------------------------------------------------------------
__global__ __launch_bounds__(256, 2)
void pq_kernel(const float* __restrict__ x, const float* __restrict__ W1,
               const float* __restrict__ b1,
               unsigned short* __restrict__ Pb, unsigned short* __restrict__ Qb)
{
    __shared__ float sXT[128 * 68];   // x^T tile, [k][row], stride 68
    __shared__ float sB[32 * 128];
    const int t = threadIdx.x;
    const int nb = blockIdx.x * 64;
    const int r0 = (t >> 4) << 2, c0 = (t & 15) << 3;

#pragma unroll
    for (int p = 0; p < 8; ++p) {
        int f = t + p * 256;                   // 2048 float4 = 64 rows x 32
        int row = f >> 5, c4 = (f & 31) << 2;
        int node = nb + row; if (node >= NN) node = NN - 1;
        float4 v = *(const float4*)(x + (long)node * DD + c4);
        sXT[(c4 + 0) * 68 + row] = v.x;
        sXT[(c4 + 1) * 68 + row] = v.y;
        sXT[(c4 + 2) * 68 + row] = v.z;
        sXT[(c4 + 3) * 68 + row] = v.w;
    }

    for (int pass = 0; pass < 2; ++pass) {
        const float* W = W1 + (pass == 0 ? 0 : 256 * DD);
        float acc[4][8];
#pragma unroll
        for (int i = 0; i < 4; ++i)
#pragma unroll
            for (int j = 0; j < 8; ++j) acc[i][j] = 0.f;

        for (int kc = 0; kc < 4; ++kc) {
            __syncthreads();
#pragma unroll
            for (int p = 0; p < 4; ++p) {
                int f = t + p * 256;           // 1024 float4 = 32 k x 32
                int kr = f >> 5, col = (f & 31) << 2;
                *(float4*)(sB + kr * 128 + col) =
                    *(const float4*)(W + (long)(kc * 32 + kr) * DD + col);
            }
            __syncthreads();
#pragma unroll 4
            for (int k = 0; k < 32; ++k) {
                float4 a  = *(const float4*)(sXT + (kc * 32 + k) * 68 + r0);
                float4 bl = *(const float4*)(sB + k * 128 + c0);
                float4 bh = *(const float4*)(sB + k * 128 + c0 + 4);
                float av[4] = {a.x, a.y, a.z, a.w};
                float bv[8] = {bl.x, bl.y, bl.z, bl.w, bh.x, bh.y, bh.z, bh.w};
#pragma unroll
                for (int i = 0; i < 4; ++i)
#pragma unroll
                    for (int j = 0; j < 8; ++j)
                        acc[i][j] = fmaf(av[i], bv[j], acc[i][j]);
            }
        }
        unsigned short* Out = (pass == 0) ? Pb : Qb;
#pragma unroll
        for (int i = 0; i < 4; ++i) {
            int node = nb + r0 + i;
            if (node < NN) {
                unsigned short tmp[8];
#pragma unroll
                for (int j = 0; j < 8; ++j) {
                    float v = acc[i][j] + (pass == 0 ? b1[c0 + j] : 0.f);
                    tmp[j] = f2bf(v);
                }
                *(uint4*)(Out + (long)node * 128 + c0) = *(uint4*)tmp;
            }
        }
    }
}

// ---------------------------------------------------------------------------
// single block, 1024 threads: exclusive scan of counts -> cursor (=offsets),
// cnt = (float)count.  10 nodes/thread.
// ---------------------------------------------------------------------------
__global__ __launch_bounds__(1024)
void scan_kernel(int* __restrict__ cursor, float* __restrict__ cnt)
{
    __shared__ int sp[1024];
    const int t = threadIdx.x;
    const int base = t * 10;                  // 1024*10 = 10240 >= NN
    int v[10], loc[10];
    int s = 0;
#pragma unroll
    for (int i = 0; i < 10; ++i) {
        int n = base + i;
        v[i] = (n < NN) ? cursor[n] : 0;
        loc[i] = s; s += v[i];
    }
    sp[t] = s;
    __syncthreads();
    // inclusive Hillis-Steele scan over 1024 partials
    for (int off = 1; off < 1024; off <<= 1) {
        int x = 0;
        if (t >= off) x = sp[t - off];
        __syncthreads();
        sp[t] += x;
        __syncthreads();
    }
    int excl = sp[t] - s;
#pragma unroll
    for (int i = 0; i < 10; ++i) {
        int n = base + i;
        if (n < NN) {
            cursor[n] = excl + loc[i];        // exclusive offset
            cnt[n] = (float)v[i];             // exact in-degree
        }
    }
}

__global__ void scatter_kernel(const int* __restrict__ ei,
                               int* __restrict__ cursor, int* __restrict__ perm)
{
    int e = blockIdx.x * 256 + threadIdx.x;
    if (e < NE) {
        int d = ei[(long)NE + e];
        int p = atomicAdd(cursor + d, 1);
        perm[p] = e;
    }
}

// ---------------------------------------------------------------------------
// Edge kernel: 128 sorted edges/block, 4 waves; wave w owns rows 32w..32w+31.
// LDS: 1.5 KB aux + 33 KB tile (bf16 A / fp32 sM overlay) = 34.5 KB.
// B-fragments read directly from global WT (96 KB, L2-hot, broadcast).
// ---------------------------------------------------------------------------
__device__ __forceinline__ const short8* frag(const unsigned short* buf,
                                              int row, int kc, int q)
{
    int g = (kc * 4 + q) ^ (row & 7);
    return (const short8*)(buf + row * 128 + g * 8);
}

__global__ __launch_bounds__(256, 2)
void edge_mfma(const float* __restrict__ ea, const int* __restrict__ ei,
               const int* __restrict__ perm,
               const unsigned short* __restrict__ WT,
               const unsigned short* __restrict__ Pb,
               const unsigned short* __restrict__ Qb,
               const float* __restrict__ b2, const float* __restrict__ b3,
               float* __restrict__ sums)
{
    __shared__ __align__(16) char smem[1536 + 64 * 132 * 4];   // 35328 B
    int*            sE   = (int*)smem;                  // [128] edge ids
    int*            sDst = (int*)(smem + 512);          // [128] dst node
    int*            sSrc = (int*)(smem + 1024);         // [128] src node
    unsigned short* sA = (unsigned short*)(smem + 1536);// 32 KB bf16 (swz)
    float*          sM = (float*)(smem + 1536);         // 64x132 fp32 overlay

    const int t = threadIdx.x;
    const int wave = t >> 6, lane = t & 63;
    const int ln = lane & 15, q = lane >> 4;
    const int r0 = wave * 32;
    const long pbase = (long)blockIdx.x * 128;

    if (t < 128) {
        int e = perm[pbase + t];
        sE[t] = e;
        sDst[t] = ei[(long)NE + e];
        sSrc[t] = ei[e];
    }
    __syncthreads();

    // stage A = bf16(ea rows, gathered via perm), swizzled; 512B/row contiguous
#pragma unroll
    for (int p = 0; p < 16; ++p) {
        int f = t + p * 256;                   // 4096 float4 = 128 x 32
        int row = f >> 5, c4 = (f & 31) << 2;
        float4 v = *(const float4*)(ea + (long)sE[row] * DD + c4);
        uint2 pk;
        pk.x = (unsigned)f2bf(v.x) | ((unsigned)f2bf(v.y) << 16);
        pk.y = (unsigned)f2bf(v.z) | ((unsigned)f2bf(v.w) << 16);
        int addr = row * 128 + ((((c4 >> 3) ^ (row & 7)) << 3) | (c4 & 7));
        *(uint2*)(sA + addr) = pk;
    }
    __syncthreads();

    f32x4 acc[2][8];

    // ---- layer 1: bf16(ea) @ W1b^T ; B-frags from global WT ----
#pragma unroll
    for (int rt = 0; rt < 2; ++rt)
#pragma unroll
        for (int ct = 0; ct < 8; ++ct) acc[rt][ct] = (f32x4)(0.f);
#pragma unroll
    for (int kc = 0; kc < 4; ++kc) {
        short8 a0 = *frag(sA, r0 + ln,      kc, q);
        short8 a1 = *frag(sA, r0 + 16 + ln, kc, q);
#pragma unroll
        for (int ct = 0; ct < 8; ++ct) {
            short8 b = *frag(WT, ct * 16 + ln, kc, q);
            acc[0][ct] = __builtin_amdgcn_mfma_f32_16x16x32_bf16(a0, b, acc[0][ct], 0, 0, 0);
            acc[1][ct] = __builtin_amdgcn_mfma_f32_16x16x32_bf16(a1, b, acc[1][ct], 0, 0, 0);
        }
    }
    __syncthreads();   // all waves done reading sA before Q overwrite

    // stage Q[src] rows into sA (swizzled), coalesced 16B/lane
#pragma unroll
    for (int p = 0; p < 8; ++p) {
        int f = t + p * 256;                   // 2048 uint4 = 128 rows x 16
        int row = f >> 4, g = f & 15;
        uint4 v = *(const uint4*)(Qb + (long)sSrc[row] * DD + g * 8);
        *(uint4*)(sA + row * 128 + ((g ^ (row & 7)) << 3)) = v;
    }
    __syncthreads();

    // epilogue-1: relu(acc + P'[dst] + Q[src]) -> sA in place (lane-private)
#pragma unroll
    for (int rt = 0; rt < 2; ++rt)
#pragma unroll
        for (int rg = 0; rg < 4; ++rg) {
            int row = r0 + rt * 16 + q * 4 + rg;
            long dof = (long)sDst[row] * DD;
#pragma unroll
            for (int ct = 0; ct < 8; ++ct) {
                int col = ct * 16 + ln;
                int slot = row * 128 + ((((col >> 3) ^ (row & 7)) << 3) | (col & 7));
                float v = acc[rt][ct][rg] + bf2f(Pb[dof + col]) + bf2f(sA[slot]);
                sA[slot] = f2bf(fmaxf(v, 0.f));
            }
        }
    // wave-private rows: no barrier needed before layer 2

    // ---- layer 2 ----
#pragma unroll
    for (int rt = 0; rt < 2; ++rt)
#pragma unroll
        for (int ct = 0; ct < 8; ++ct) acc[rt][ct] = (f32x4)(0.f);
#pragma unroll
    for (int kc = 0; kc < 4; ++kc) {
        short8 a0 = *frag(sA, r0 + ln,      kc, q);
        short8 a1 = *frag(sA, r0 + 16 + ln, kc, q);
#pragma unroll
        for (int ct = 0; ct < 8; ++ct) {
            short8 b = *frag(WT + 16384, ct * 16 + ln, kc, q);
            acc[0][ct] = __builtin_amdgcn_mfma_f32_16x16x32_bf16(a0, b, acc[0][ct], 0, 0, 0);
            acc[1][ct] = __builtin_amdgcn_mfma_f32_16x16x32_bf16(a1, b, acc[1][ct], 0, 0, 0);
        }
    }
    // epilogue-2: relu(acc + b2) -> sA in place (lane-private)
    float bv2[8];
#pragma unroll
    for (int ct = 0; ct < 8; ++ct) bv2[ct] = b2[ct * 16 + ln];
#pragma unroll
    for (int rt = 0; rt < 2; ++rt)
#pragma unroll
        for (int rg = 0; rg < 4; ++rg) {
            int row = r0 + rt * 16 + q * 4 + rg;
#pragma unroll
            for (int ct = 0; ct < 8; ++ct) {
                int col = ct * 16 + ln;
                int slot = row * 128 + ((((col >> 3) ^ (row & 7)) << 3) | (col & 7));
                sA[slot] = f2bf(fmaxf(acc[rt][ct][rg] + bv2[ct], 0.f));
            }
        }

    // ---- layer 3 ----
#pragma unroll
    for (int rt = 0; rt < 2; ++rt)
#pragma unroll
        for (int ct = 0; ct < 8; ++ct) acc[rt][ct] = (f32x4)(0.f);
#pragma unroll
    for (int kc = 0; kc < 4; ++kc) {
        short8 a0 = *frag(sA, r0 + ln,      kc, q);
        short8 a1 = *frag(sA, r0 + 16 + ln, kc, q);
#pragma unroll
        for (int ct = 0; ct < 8; ++ct) {
            short8 b = *frag(WT + 2 * 16384, ct * 16 + ln, kc, q);
            acc[0][ct] = __builtin_amdgcn_mfma_f32_16x16x32_bf16(a0, b, acc[0][ct], 0, 0, 0);
            acc[1][ct] = __builtin_amdgcn_mfma_f32_16x16x32_bf16(a1, b, acc[1][ct], 0, 0, 0);
        }
    }
    __syncthreads();   // sA dead; sM overlay begins

    // epilogue-3: two 64-row chunks; fp32 stage into sM (stride 132), then
    // segmented reduction over sorted dst -> few atomics.
    float bv3[8];
#pragma unroll
    for (int ct = 0; ct < 8; ++ct) bv3[ct] = b3[ct * 16 + ln];

    // chunk 0: rows 0..63 (waves 0,1)
    if (wave < 2) {
#pragma unroll
        for (int rt = 0; rt < 2; ++rt)
#pragma unroll
            for (int rg = 0; rg < 4; ++rg) {
                int row = r0 + rt * 16 + q * 4 + rg;
#pragma unroll
                for (int ct = 0; ct < 8; ++ct)
                    sM[row * 132 + ct * 16 + ln] = acc[rt][ct][rg] + bv3[ct];
            }
    }
    __syncthreads();
    {
        const int c = t & 127, h = t >> 7;
        const int rb = h * 32;
        float a = 0.f;
        int cur = sDst[rb];
#pragma unroll 8
        for (int r = rb; r < rb + 32; ++r) {
            int d = sDst[r];                   // LDS broadcast
            if (d != cur) {
                atomicAdd(sums + (long)cur * DD + c, a);
                a = 0.f; cur = d;
            }
            a += sM[r * 132 + c];
        }
        atomicAdd(sums + (long)cur * DD + c, a);
    }
    __syncthreads();
    // chunk 1: rows 64..127 (waves 2,3)
    if (wave >= 2) {
#pragma unroll
        for (int rt = 0; rt < 2; ++rt)
#pragma unroll
            for (int rg = 0; rg < 4; ++rg) {
                int row = r0 + rt * 16 + q * 4 + rg;   // 64..127
#pragma unroll
                for (int ct = 0; ct < 8; ++ct)
                    sM[(row - 64) * 132 + ct * 16 + ln] = acc[rt][ct][rg] + bv3[ct];
            }
    }
    __syncthreads();
    {
        const int c = t & 127, h = t >> 7;
        const int rb = h * 32;
        float a = 0.f;
        int cur = sDst[64 + rb];
#pragma unroll 8
        for (int r = rb; r < rb + 32; ++r) {
            int d = sDst[64 + r];
            if (d != cur) {
                atomicAdd(sums + (long)cur * DD + c, a);
                a = 0.f; cur = d;
            }
            a += sM[r * 132 + c];
        }
        atomicAdd(sums + (long)cur * DD + c, a);
    }
}

// ---------------------------------------------------------------------------
// Node stage: dh + LN1 + FF + LN2, fp32, 8 nodes/block.
// ---------------------------------------------------------------------------
__global__ __launch_bounds__(256)
void node_fused(const float* __restrict__ x,
                const float* __restrict__ sums, const float* __restrict__ cnt,
                const float* __restrict__ F1, const float* __restrict__ bf1,
                const float* __restrict__ F2, const float* __restrict__ bf2,
                const float* __restrict__ g0, const float* __restrict__ be0,
                const float* __restrict__ g1, const float* __restrict__ be1,
                float* __restrict__ out)
{
    constexpr int NPB = 8;
    __shared__ float sh[NPB][DD];
    __shared__ float shid[NPB][HIDN];
    __shared__ float sz[NPB][DD];

    const int t = threadIdx.x;
    const int wave = t >> 6, lane = t & 63;
    const int half = lane >> 5, l2 = lane & 31;
    const int nl = wave * 2 + half;
    const int node = blockIdx.x * NPB + nl;
    const long base = (long)node * DD;

    float inv = 1.0f / fmaxf(cnt[node], 1.0f);
    float y[4], s = 0.f, ss = 0.f;
#pragma unroll
    for (int e = 0; e < 4; ++e) {
        int c = l2 + 32 * e;
        y[e] = x[base + c] + sums[base + c] * inv;
        s += y[e]; ss += y[e] * y[e];
    }
#pragma unroll
    for (int off = 16; off > 0; off >>= 1) {
        s += __shfl_down(s, off, 32); ss += __shfl_down(ss, off, 32);
    }
    s = __shfl(s, 0, 32); ss = __shfl(ss, 0, 32);
    float mean = s * (1.0f / DD);
    float var  = ss * (1.0f / DD) - mean * mean;
    float rstd = rsqrtf(var + EPSF);
#pragma unroll
    for (int e = 0; e < 4; ++e) {
        int c = l2 + 32 * e;
        sh[nl][c] = (y[e] - mean) * rstd * g0[c] + be0[c];
    }
    __syncthreads();

    float hacc[NPB];
    float bb = bf1[t];
#pragma unroll
    for (int v = 0; v < NPB; ++v) hacc[v] = bb;
    for (int k = 0; k < DD; ++k) {
        float wv = F1[(long)k * HIDN + t];
#pragma unroll
        for (int v = 0; v < NPB; ++v) hacc[v] = fmaf(sh[v][k], wv, hacc[v]);
    }
#pragma unroll
    for (int v = 0; v < NPB; ++v) shid[v][t] = fmaxf(hacc[v], 0.f);
    __syncthreads();

    const int col = t & (DD - 1);
    const int grp = (t >> 7) * 4;
    float o[4];
#pragma unroll
    for (int v = 0; v < 4; ++v) o[v] = bf2[col];
    for (int k = 0; k < HIDN; ++k) {
        float wv = F2[(long)k * DD + col];
#pragma unroll
        for (int v = 0; v < 4; ++v) o[v] = fmaf(shid[grp + v][k], wv, o[v]);
    }
#pragma unroll
    for (int v = 0; v < 4; ++v) sz[grp + v][col] = sh[grp + v][col] + o[v];
    __syncthreads();

    float z[4]; s = 0.f; ss = 0.f;
#pragma unroll
    for (int e = 0; e < 4; ++e) {
        int c = l2 + 32 * e;
        z[e] = sz[nl][c]; s += z[e]; ss += z[e] * z[e];
    }
#pragma unroll
    for (int off = 16; off > 0; off >>= 1) {
        s += __shfl_down(s, off, 32); ss += __shfl_down(ss, off, 32);
    }
    s = __shfl(s, 0, 32); ss = __shfl(ss, 0, 32);
    mean = s * (1.0f / DD);
    var  = ss * (1.0f / DD) - mean * mean;
    rstd = rsqrtf(var + EPSF);
#pragma unroll
    for (int e = 0; e < 4; ++e) {
        int c = l2 + 32 * e;
        out[base + c] = (z[e] - mean) * rstd * g1[c] + be1[c];
    }
}

extern "C" void kernel_launch(void* const* d_in, const int* in_sizes, int n_in,
                              void* d_out, int out_size, void* d_ws, size_t ws_size,
                              hipStream_t stream)
{
    const float* x   = (const float*)d_in[0];
    const int*   ei  = (const int*)  d_in[1];
    const float* ea  = (const float*)d_in[2];
    const float* W1  = (const float*)d_in[3];
    const float* b1  = (const float*)d_in[4];
    const float* W2  = (const float*)d_in[5];
    const float* b2  = (const float*)d_in[6];
    const float* W3  = (const float*)d_in[7];
    const float* b3  = (const float*)d_in[8];
    const float* F1  = (const float*)d_in[9];
    const float* bf1 = (const float*)d_in[10];
    const float* F2  = (const float*)d_in[11];
    const float* bf2 = (const float*)d_in[12];
    const float* g0  = (const float*)d_in[13];
    const float* be0 = (const float*)d_in[14];
    const float* g1  = (const float*)d_in[15];
    const float* be1 = (const float*)d_in[16];
    float* out = (float*)d_out;

    char* ws = (char*)d_ws;
    float*          sums   = (float*)(ws);                     // 5,120,000 B
    float*          cnt    = (float*)(ws + 5120000);           //    40,000 B
    unsigned short* WT     = (unsigned short*)(ws + 5160192);  //    98,304 B
    unsigned short* Pb     = (unsigned short*)(ws + 5258752);  // 2,560,000 B
    unsigned short* Qb     = (unsigned short*)(ws + 7818752);  // 2,560,000 B
    int*            cursor = (int*)(ws + 10378752);            //    40,000 B
    int*            perm   = (int*)(ws + 10418752);            // 2,560,000 B
    // total ~12.98 MB

    hipMemsetAsync(ws, 0, 5120000, stream);                    // sums
    hipMemsetAsync(ws + 10378752, 0, 40000, stream);           // cursor
    prep_hist<<<NE / 256, 256, 0, stream>>>(W1, W2, W3, WT, ei, cursor);
    pq_kernel<<<(NN + 63) / 64, 256, 0, stream>>>(x, W1, b1, Pb, Qb);
    scan_kernel<<<1, 1024, 0, stream>>>(cursor, cnt);
    scatter_kernel<<<NE / 256, 256, 0, stream>>>(ei, cursor, perm);
    edge_mfma<<<NE / 128, 256, 0, stream>>>(ea, ei, perm, WT, Pb, Qb,
                                            b2, b3, sums);
    node_fused<<<NN / 8, 256, 0, stream>>>(x, sums, cnt, F1, bf1, F2, bf2,
                                           g0, be0, g1, be1, out);
}

// Round 4
// 781.552 us; speedup vs baseline: 1.1629x; 1.1020x over previous
//
#include <hip/hip_runtime.h>

// NodeMPNNLayer — bf16-MFMA + dst-sorted edges.
//   prep_hist:    W1b/W2/W3 -> bf16 swizzled in ws  +  dst histogram.
//   pq_kernel:    P' = x@W1[0:128] + b1,  Q = x@W1[256:384]   (bf16 in ws)
//   scan/scatter: counting-sort edge ids by dst -> perm[], exact cnt[].
//   edge_mfma:    128 sorted edges/block; W in LDS (restaged per layer —
//                 R3 showed global B-frags add ~200cy L2 latency per kc and
//                 cost +86us at equal occupancy); Q[src] staged coalesced
//                 into the dead A-buffer; in-place lane-private epilogues;
//                 padded fp32 overlay + segmented-reduction scatter.
//                 launch_bounds(256,2): (256,4) forced 64-VGPR spills (R2).
//   node_fused:   dh=sums/max(cnt,1); LN; FF; LN  (fp32, 8 nodes/block,
//                 unroll-8 GEMM loops for load pipelining).

#define NE 640000
#define NN 10000
#define DD 128
#define HIDN 256
#define EPSF 1e-6f

typedef __attribute__((ext_vector_type(8))) short short8;
typedef __attribute__((ext_vector_type(4))) float f32x4;

__device__ __forceinline__ unsigned short f2bf(float f) {
    union { float f; unsigned int u; } v; v.f = f;
    unsigned int r = v.u + 0x7FFFu + ((v.u >> 16) & 1u);
    return (unsigned short)(r >> 16);
}
__device__ __forceinline__ float bf2f(unsigned short h) {
    union { unsigned int u; float f; } v; v.u = ((unsigned int)h) << 16;
    return v.f;
}

// ---------------------------------------------------------------------------
// Fused weight prep + dst histogram.  grid = NE/256 = 2500 blocks.
// ---------------------------------------------------------------------------
__global__ void prep_hist(const float* __restrict__ W1,
                          const float* __restrict__ W2,
                          const float* __restrict__ W3,
                          unsigned short* __restrict__ WT,
                          const int* __restrict__ ei,
                          int* __restrict__ cursor)
{
    int e = blockIdx.x * 256 + threadIdx.x;
    if (e < NE) atomicAdd(cursor + ei[(long)NE + e], 1);
    if (blockIdx.x < 192) {
        int g = blockIdx.x * 256 + threadIdx.x;  // 3*16384 = 49152
        int layer = g >> 14, r = g & 16383;
        int n = r >> 7, k = r & 127;
        const float* W = (layer == 0) ? (W1 + 128 * DD) : (layer == 1 ? W2 : W3);
        WT[layer * 16384 + n * 128 + ((((k >> 3) ^ (n & 7)) << 3) | (k & 7))] =
            f2bf(W[k * DD + n]);
    }
}

// ---------------------------------------------------------------------------
// P' = x @ W1[0:128] + b1 ; Q = x @ W1[256:384]   (outputs bf16)
// ---------------------------------------------------------------------------
__global__ __launch_bounds__(256, 2)
void pq_kernel(const float* __restrict__ x, const float* __restrict__ W1,
               const float* __restrict__ b1,
               unsigned short* __restrict__ Pb, unsigned short* __restrict__ Qb)
{
    __shared__ float sXT[128 * 68];   // x^T tile, [k][row], stride 68
    __shared__ float sB[32 * 128];
    const int t = threadIdx.x;
    const int nb = blockIdx.x * 64;
    const int r0 = (t >> 4) << 2, c0 = (t & 15) << 3;

#pragma unroll
    for (int p = 0; p < 8; ++p) {
        int f = t + p * 256;                   // 2048 float4 = 64 rows x 32
        int row = f >> 5, c4 = (f & 31) << 2;
        int node = nb + row; if (node >= NN) node = NN - 1;
        float4 v = *(const float4*)(x + (long)node * DD + c4);
        sXT[(c4 + 0) * 68 + row] = v.x;
        sXT[(c4 + 1) * 68 + row] = v.y;
        sXT[(c4 + 2) * 68 + row] = v.z;
        sXT[(c4 + 3) * 68 + row] = v.w;
    }

    for (int pass = 0; pass < 2; ++pass) {
        const float* W = W1 + (pass == 0 ? 0 : 256 * DD);
        float acc[4][8];
#pragma unroll
        for (int i = 0; i < 4; ++i)
#pragma unroll
            for (int j = 0; j < 8; ++j) acc[i][j] = 0.f;

        for (int kc = 0; kc < 4; ++kc) {
            __syncthreads();
#pragma unroll
            for (int p = 0; p < 4; ++p) {
                int f = t + p * 256;           // 1024 float4 = 32 k x 32
                int kr = f >> 5, col = (f & 31) << 2;
                *(float4*)(sB + kr * 128 + col) =
                    *(const float4*)(W + (long)(kc * 32 + kr) * DD + col);
            }
            __syncthreads();
#pragma unroll 4
            for (int k = 0; k < 32; ++k) {
                float4 a  = *(const float4*)(sXT + (kc * 32 + k) * 68 + r0);
                float4 bl = *(const float4*)(sB + k * 128 + c0);
                float4 bh = *(const float4*)(sB + k * 128 + c0 + 4);
                float av[4] = {a.x, a.y, a.z, a.w};
                float bv[8] = {bl.x, bl.y, bl.z, bl.w, bh.x, bh.y, bh.z, bh.w};
#pragma unroll
                for (int i = 0; i < 4; ++i)
#pragma unroll
                    for (int j = 0; j < 8; ++j)
                        acc[i][j] = fmaf(av[i], bv[j], acc[i][j]);
            }
        }
        unsigned short* Out = (pass == 0) ? Pb : Qb;
#pragma unroll
        for (int i = 0; i < 4; ++i) {
            int node = nb + r0 + i;
            if (node < NN) {
                unsigned short tmp[8];
#pragma unroll
                for (int j = 0; j < 8; ++j) {
                    float v = acc[i][j] + (pass == 0 ? b1[c0 + j] : 0.f);
                    tmp[j] = f2bf(v);
                }
                *(uint4*)(Out + (long)node * 128 + c0) = *(uint4*)tmp;
            }
        }
    }
}

// ---------------------------------------------------------------------------
// single block, 1024 threads: exclusive scan of counts -> cursor (=offsets),
// cnt = (float)count.  10 nodes/thread.
// ---------------------------------------------------------------------------
__global__ __launch_bounds__(1024)
void scan_kernel(int* __restrict__ cursor, float* __restrict__ cnt)
{
    __shared__ int sp[1024];
    const int t = threadIdx.x;
    const int base = t * 10;                  // 1024*10 = 10240 >= NN
    int v[10], loc[10];
    int s = 0;
#pragma unroll
    for (int i = 0; i < 10; ++i) {
        int n = base + i;
        v[i] = (n < NN) ? cursor[n] : 0;
        loc[i] = s; s += v[i];
    }
    sp[t] = s;
    __syncthreads();
    for (int off = 1; off < 1024; off <<= 1) {
        int x = 0;
        if (t >= off) x = sp[t - off];
        __syncthreads();
        sp[t] += x;
        __syncthreads();
    }
    int excl = sp[t] - s;
#pragma unroll
    for (int i = 0; i < 10; ++i) {
        int n = base + i;
        if (n < NN) {
            cursor[n] = excl + loc[i];        // exclusive offset
            cnt[n] = (float)v[i];             // exact in-degree
        }
    }
}

__global__ void scatter_kernel(const int* __restrict__ ei,
                               int* __restrict__ cursor, int* __restrict__ perm)
{
    int e = blockIdx.x * 256 + threadIdx.x;
    if (e < NE) {
        int d = ei[(long)NE + e];
        int p = atomicAdd(cursor + d, 1);
        perm[p] = e;
    }
}

// ---------------------------------------------------------------------------
// Edge kernel: 128 sorted edges/block, 4 waves; wave w owns rows 32w..32w+31.
// LDS: 1.5 KB aux + 32 KB sA + 32 KB sW = 67072 B -> 2 blocks/CU.
// ---------------------------------------------------------------------------
__device__ __forceinline__ const short8* frag(const unsigned short* buf,
                                              int row, int kc, int q)
{
    int g = (kc * 4 + q) ^ (row & 7);
    return (const short8*)(buf + row * 128 + g * 8);
}

__global__ __launch_bounds__(256, 2)
void edge_mfma(const float* __restrict__ ea, const int* __restrict__ ei,
               const int* __restrict__ perm,
               const unsigned short* __restrict__ WT,
               const unsigned short* __restrict__ Pb,
               const unsigned short* __restrict__ Qb,
               const float* __restrict__ b2, const float* __restrict__ b3,
               float* __restrict__ sums)
{
    __shared__ __align__(16) char smem[1536 + 65536];   // 67072 B
    int*            sE   = (int*)smem;                  // [128] edge ids
    int*            sDst = (int*)(smem + 512);          // [128] dst node
    int*            sSrc = (int*)(smem + 1024);         // [128] src node
    unsigned short* sA = (unsigned short*)(smem + 1536);        // 32 KB
    unsigned short* sW = (unsigned short*)(smem + 1536 + 32768);// 32 KB
    float*          sM = (float*)(smem + 1536);         // 64x132 fp32 overlay

    const int t = threadIdx.x;
    const int wave = t >> 6, lane = t & 63;
    const int ln = lane & 15, q = lane >> 4;
    const int r0 = wave * 32;
    const long pbase = (long)blockIdx.x * 128;

    if (t < 128) {
        int e = perm[pbase + t];
        sE[t] = e;
        sDst[t] = ei[(long)NE + e];
        sSrc[t] = ei[e];
    }
    // stage W1 into sW (pre-swizzled: pure linear copy)
    {
        const uint4* src = (const uint4*)WT;
        uint4* dst = (uint4*)sW;
#pragma unroll
        for (int p = 0; p < 8; ++p) dst[t + p * 256] = src[t + p * 256];
    }
    __syncthreads();

    int drow[8];
#pragma unroll
    for (int rt = 0; rt < 2; ++rt)
#pragma unroll
        for (int rg = 0; rg < 4; ++rg)
            drow[rt * 4 + rg] = sDst[r0 + rt * 16 + q * 4 + rg];

    // stage A = bf16(ea rows, gathered via perm), swizzled; 512B/row contiguous
#pragma unroll
    for (int p = 0; p < 16; ++p) {
        int f = t + p * 256;                   // 4096 float4 = 128 x 32
        int row = f >> 5, c4 = (f & 31) << 2;
        float4 v = *(const float4*)(ea + (long)sE[row] * DD + c4);
        uint2 pk;
        pk.x = (unsigned)f2bf(v.x) | ((unsigned)f2bf(v.y) << 16);
        pk.y = (unsigned)f2bf(v.z) | ((unsigned)f2bf(v.w) << 16);
        int addr = row * 128 + ((((c4 >> 3) ^ (row & 7)) << 3) | (c4 & 7));
        *(uint2*)(sA + addr) = pk;
    }
    __syncthreads();

    f32x4 acc[2][8];

    // ---- layer 1: bf16(ea) @ W1b^T ----
#pragma unroll
    for (int rt = 0; rt < 2; ++rt)
#pragma unroll
        for (int ct = 0; ct < 8; ++ct) acc[rt][ct] = (f32x4)(0.f);
#pragma unroll
    for (int kc = 0; kc < 4; ++kc) {
        short8 a0 = *frag(sA, r0 + ln,      kc, q);
        short8 a1 = *frag(sA, r0 + 16 + ln, kc, q);
#pragma unroll
        for (int ct = 0; ct < 8; ++ct) {
            short8 b = *frag(sW, ct * 16 + ln, kc, q);
            acc[0][ct] = __builtin_amdgcn_mfma_f32_16x16x32_bf16(a0, b, acc[0][ct], 0, 0, 0);
            acc[1][ct] = __builtin_amdgcn_mfma_f32_16x16x32_bf16(a1, b, acc[1][ct], 0, 0, 0);
        }
    }
    __syncthreads();   // all waves done reading sA & sW

    // restage sW = W2 ; stage Q[src] rows into sA (coalesced 16B/lane)
    {
        const uint4* src = (const uint4*)(WT + 16384);
        uint4* dst = (uint4*)sW;
#pragma unroll
        for (int p = 0; p < 8; ++p) dst[t + p * 256] = src[t + p * 256];
    }
#pragma unroll
    for (int p = 0; p < 8; ++p) {
        int f = t + p * 256;                   // 2048 uint4 = 128 rows x 16
        int row = f >> 4, g = f & 15;
        uint4 v = *(const uint4*)(Qb + (long)sSrc[row] * DD + g * 8);
        *(uint4*)(sA + row * 128 + ((g ^ (row & 7)) << 3)) = v;
    }
    __syncthreads();

    // epilogue-1: relu(acc + P'[dst] + Q[src]) -> sA in place (lane-private)
#pragma unroll
    for (int rt = 0; rt < 2; ++rt)
#pragma unroll
        for (int rg = 0; rg < 4; ++rg) {
            int row = r0 + rt * 16 + q * 4 + rg;
            long dof = (long)drow[rt * 4 + rg] * DD;
#pragma unroll
            for (int ct = 0; ct < 8; ++ct) {
                int col = ct * 16 + ln;
                int slot = row * 128 + ((((col >> 3) ^ (row & 7)) << 3) | (col & 7));
                float v = acc[rt][ct][rg] + bf2f(Pb[dof + col]) + bf2f(sA[slot]);
                sA[slot] = f2bf(fmaxf(v, 0.f));
            }
        }
    // lane-private rows: no barrier before layer 2

    // ---- layer 2 ----
#pragma unroll
    for (int rt = 0; rt < 2; ++rt)
#pragma unroll
        for (int ct = 0; ct < 8; ++ct) acc[rt][ct] = (f32x4)(0.f);
#pragma unroll
    for (int kc = 0; kc < 4; ++kc) {
        short8 a0 = *frag(sA, r0 + ln,      kc, q);
        short8 a1 = *frag(sA, r0 + 16 + ln, kc, q);
#pragma unroll
        for (int ct = 0; ct < 8; ++ct) {
            short8 b = *frag(sW, ct * 16 + ln, kc, q);
            acc[0][ct] = __builtin_amdgcn_mfma_f32_16x16x32_bf16(a0, b, acc[0][ct], 0, 0, 0);
            acc[1][ct] = __builtin_amdgcn_mfma_f32_16x16x32_bf16(a1, b, acc[1][ct], 0, 0, 0);
        }
    }
    __syncthreads();   // all waves done reading sA & sW

    // restage sW = W3 ; epilogue-2: relu(acc + b2) -> sA in place
    {
        const uint4* src = (const uint4*)(WT + 2 * 16384);
        uint4* dst = (uint4*)sW;
#pragma unroll
        for (int p = 0; p < 8; ++p) dst[t + p * 256] = src[t + p * 256];
    }
    float bv2[8];
#pragma unroll
    for (int ct = 0; ct < 8; ++ct) bv2[ct] = b2[ct * 16 + ln];
#pragma unroll
    for (int rt = 0; rt < 2; ++rt)
#pragma unroll
        for (int rg = 0; rg < 4; ++rg) {
            int row = r0 + rt * 16 + q * 4 + rg;
#pragma unroll
            for (int ct = 0; ct < 8; ++ct) {
                int col = ct * 16 + ln;
                int slot = row * 128 + ((((col >> 3) ^ (row & 7)) << 3) | (col & 7));
                sA[slot] = f2bf(fmaxf(acc[rt][ct][rg] + bv2[ct], 0.f));
            }
        }
    __syncthreads();   // W3 visible to all

    // ---- layer 3 ----
#pragma unroll
    for (int rt = 0; rt < 2; ++rt)
#pragma unroll
        for (int ct = 0; ct < 8; ++ct) acc[rt][ct] = (f32x4)(0.f);
#pragma unroll
    for (int kc = 0; kc < 4; ++kc) {
        short8 a0 = *frag(sA, r0 + ln,      kc, q);
        short8 a1 = *frag(sA, r0 + 16 + ln, kc, q);
#pragma unroll
        for (int ct = 0; ct < 8; ++ct) {
            short8 b = *frag(sW, ct * 16 + ln, kc, q);
            acc[0][ct] = __builtin_amdgcn_mfma_f32_16x16x32_bf16(a0, b, acc[0][ct], 0, 0, 0);
            acc[1][ct] = __builtin_amdgcn_mfma_f32_16x16x32_bf16(a1, b, acc[1][ct], 0, 0, 0);
        }
    }
    __syncthreads();   // sA/sW dead; sM overlay begins

    // epilogue-3: two 64-row chunks; fp32 stage into sM (stride 132), then
    // segmented reduction over sorted dst -> few atomics.
    float bv3[8];
#pragma unroll
    for (int ct = 0; ct < 8; ++ct) bv3[ct] = b3[ct * 16 + ln];

    // chunk 0: rows 0..63 (waves 0,1)
    if (wave < 2) {
#pragma unroll
        for (int rt = 0; rt < 2; ++rt)
#pragma unroll
            for (int rg = 0; rg < 4; ++rg) {
                int row = r0 + rt * 16 + q * 4 + rg;
#pragma unroll
                for (int ct = 0; ct < 8; ++ct)
                    sM[row * 132 + ct * 16 + ln] = acc[rt][ct][rg] + bv3[ct];
            }
    }
    __syncthreads();
    {
        const int c = t & 127, h = t >> 7;
        const int rb = h * 32;
        float a = 0.f;
        int cur = sDst[rb];
#pragma unroll 8
        for (int r = rb; r < rb + 32; ++r) {
            int d = sDst[r];                   // LDS broadcast
            if (d != cur) {
                atomicAdd(sums + (long)cur * DD + c, a);
                a = 0.f; cur = d;
            }
            a += sM[r * 132 + c];
        }
        atomicAdd(sums + (long)cur * DD + c, a);
    }
    __syncthreads();
    // chunk 1: rows 64..127 (waves 2,3)
    if (wave >= 2) {
#pragma unroll
        for (int rt = 0; rt < 2; ++rt)
#pragma unroll
            for (int rg = 0; rg < 4; ++rg) {
                int row = r0 + rt * 16 + q * 4 + rg;   // 64..127
#pragma unroll
                for (int ct = 0; ct < 8; ++ct)
                    sM[(row - 64) * 132 + ct * 16 + ln] = acc[rt][ct][rg] + bv3[ct];
            }
    }
    __syncthreads();
    {
        const int c = t & 127, h = t >> 7;
        const int rb = h * 32;
        float a = 0.f;
        int cur = sDst[64 + rb];
#pragma unroll 8
        for (int r = rb; r < rb + 32; ++r) {
            int d = sDst[64 + r];
            if (d != cur) {
                atomicAdd(sums + (long)cur * DD + c, a);
                a = 0.f; cur = d;
            }
            a += sM[r * 132 + c];
        }
        atomicAdd(sums + (long)cur * DD + c, a);
    }
}

// ---------------------------------------------------------------------------
// Node stage: dh + LN1 + FF + LN2, fp32, 8 nodes/block.
// ---------------------------------------------------------------------------
__global__ __launch_bounds__(256)
void node_fused(const float* __restrict__ x,
                const float* __restrict__ sums, const float* __restrict__ cnt,
                const float* __restrict__ F1, const float* __restrict__ bf1,
                const float* __restrict__ F2, const float* __restrict__ bf2,
                const float* __restrict__ g0, const float* __restrict__ be0,
                const float* __restrict__ g1, const float* __restrict__ be1,
                float* __restrict__ out)
{
    constexpr int NPB = 8;
    __shared__ float sh[NPB][DD];
    __shared__ float shid[NPB][HIDN];
    __shared__ float sz[NPB][DD];

    const int t = threadIdx.x;
    const int wave = t >> 6, lane = t & 63;
    const int half = lane >> 5, l2 = lane & 31;
    const int nl = wave * 2 + half;
    const int node = blockIdx.x * NPB + nl;
    const long base = (long)node * DD;

    float inv = 1.0f / fmaxf(cnt[node], 1.0f);
    float y[4], s = 0.f, ss = 0.f;
#pragma unroll
    for (int e = 0; e < 4; ++e) {
        int c = l2 + 32 * e;
        y[e] = x[base + c] + sums[base + c] * inv;
        s += y[e]; ss += y[e] * y[e];
    }
#pragma unroll
    for (int off = 16; off > 0; off >>= 1) {
        s += __shfl_down(s, off, 32); ss += __shfl_down(ss, off, 32);
    }
    s = __shfl(s, 0, 32); ss = __shfl(ss, 0, 32);
    float mean = s * (1.0f / DD);
    float var  = ss * (1.0f / DD) - mean * mean;
    float rstd = rsqrtf(var + EPSF);
#pragma unroll
    for (int e = 0; e < 4; ++e) {
        int c = l2 + 32 * e;
        sh[nl][c] = (y[e] - mean) * rstd * g0[c] + be0[c];
    }
    __syncthreads();

    float hacc[NPB];
    float bb = bf1[t];
#pragma unroll
    for (int v = 0; v < NPB; ++v) hacc[v] = bb;
#pragma unroll 8
    for (int k = 0; k < DD; ++k) {
        float wv = F1[(long)k * HIDN + t];
#pragma unroll
        for (int v = 0; v < NPB; ++v) hacc[v] = fmaf(sh[v][k], wv, hacc[v]);
    }
#pragma unroll
    for (int v = 0; v < NPB; ++v) shid[v][t] = fmaxf(hacc[v], 0.f);
    __syncthreads();

    const int col = t & (DD - 1);
    const int grp = (t >> 7) * 4;
    float o[4];
#pragma unroll
    for (int v = 0; v < 4; ++v) o[v] = bf2[col];
#pragma unroll 8
    for (int k = 0; k < HIDN; ++k) {
        float wv = F2[(long)k * DD + col];
#pragma unroll
        for (int v = 0; v < 4; ++v) o[v] = fmaf(shid[grp + v][k], wv, o[v]);
    }
#pragma unroll
    for (int v = 0; v < 4; ++v) sz[grp + v][col] = sh[grp + v][col] + o[v];
    __syncthreads();

    float z[4]; s = 0.f; ss = 0.f;
#pragma unroll
    for (int e = 0; e < 4; ++e) {
        int c = l2 + 32 * e;
        z[e] = sz[nl][c]; s += z[e]; ss += z[e] * z[e];
    }
#pragma unroll
    for (int off = 16; off > 0; off >>= 1) {
        s += __shfl_down(s, off, 32); ss += __shfl_down(ss, off, 32);
    }
    s = __shfl(s, 0, 32); ss = __shfl(ss, 0, 32);
    mean = s * (1.0f / DD);
    var  = ss * (1.0f / DD) - mean * mean;
    rstd = rsqrtf(var + EPSF);
#pragma unroll
    for (int e = 0; e < 4; ++e) {
        int c = l2 + 32 * e;
        out[base + c] = (z[e] - mean) * rstd * g1[c] + be1[c];
    }
}

extern "C" void kernel_launch(void* const* d_in, const int* in_sizes, int n_in,
                              void* d_out, int out_size, void* d_ws, size_t ws_size,
                              hipStream_t stream)
{
    const float* x   = (const float*)d_in[0];
    const int*   ei  = (const int*)  d_in[1];
    const float* ea  = (const float*)d_in[2];
    const float* W1  = (const float*)d_in[3];
    const float* b1  = (const float*)d_in[4];
    const float* W2  = (const float*)d_in[5];
    const float* b2  = (const float*)d_in[6];
    const float* W3  = (const float*)d_in[7];
    const float* b3  = (const float*)d_in[8];
    const float* F1  = (const float*)d_in[9];
    const float* bf1 = (const float*)d_in[10];
    const float* F2  = (const float*)d_in[11];
    const float* bf2 = (const float*)d_in[12];
    const float* g0  = (const float*)d_in[13];
    const float* be0 = (const float*)d_in[14];
    const float* g1  = (const float*)d_in[15];
    const float* be1 = (const float*)d_in[16];
    float* out = (float*)d_out;

    char* ws = (char*)d_ws;
    float*          sums   = (float*)(ws);                     // 5,120,000 B
    float*          cnt    = (float*)(ws + 5120000);           //    40,000 B
    unsigned short* WT     = (unsigned short*)(ws + 5160192);  //    98,304 B
    unsigned short* Pb     = (unsigned short*)(ws + 5258752);  // 2,560,000 B
    unsigned short* Qb     = (unsigned short*)(ws + 7818752);  // 2,560,000 B
    int*            cursor = (int*)(ws + 10378752);            //    40,000 B
    int*            perm   = (int*)(ws + 10418752);            // 2,560,000 B
    // total ~12.98 MB

    hipMemsetAsync(ws, 0, 5120000, stream);                    // sums
    hipMemsetAsync(ws + 10378752, 0, 40000, stream);           // cursor
    prep_hist<<<NE / 256, 256, 0, stream>>>(W1, W2, W3, WT, ei, cursor);
    pq_kernel<<<(NN + 63) / 64, 256, 0, stream>>>(x, W1, b1, Pb, Qb);
    scan_kernel<<<1, 1024, 0, stream>>>(cursor, cnt);
    scatter_kernel<<<NE / 256, 256, 0, stream>>>(ei, cursor, perm);
    edge_mfma<<<NE / 128, 256, 0, stream>>>(ea, ei, perm, WT, Pb, Qb,
                                            b2, b3, sums);
    node_fused<<<NN / 8, 256, 0, stream>>>(x, sums, cnt, F1, bf1, F2, bf2,
                                           g0, be0, g1, be1, out);
}